// Round 7
// baseline (1451.228 us; speedup 1.0000x reference)
//
#include <hip/hip_runtime.h>

typedef unsigned short ushort_t;
typedef unsigned int uint_t;
typedef __attribute__((ext_vector_type(8))) short short8;

#define S_LEN 2048
#define D_DIM 1024
#define H_NUM 16
#define HD 64
#define LKP 68   // padded LDS row stride in floats

__device__ __forceinline__ float bf2f(ushort_t u) {
    union { uint_t i; float f; } c; c.i = ((uint_t)u) << 16; return c.f;
}
__device__ __forceinline__ ushort_t f2bf(float f) {
    union { float f; uint_t i; } c; c.f = f;
    uint_t r = c.i + 0x7fffu + ((c.i >> 16) & 1u);
    return (ushort_t)(r >> 16);
}

// ---------------------------------------------------------------- naive GEMM
// C[4096,1024] = A[4096,1024] @ W[1024,1024] (+bias), W row-major [d_in,d_out]
// (forward = x @ W, as stored). A is f32 (Af) or bf16 (Ab) — one non-null.
// Output: bf16 (Cb) or f32 (Cf) — exactly one non-null.
// 64x64 tile, BK=32, 256 threads as 16x16, 4x4 acc/thread, f32 LDS staging.
__global__ __launch_bounds__(256, 4) void gemm_naive_kernel(
        const float* __restrict__ Af, const ushort_t* __restrict__ Ab,
        const float* __restrict__ W, const float* __restrict__ bias,
        ushort_t* __restrict__ Cb, float* __restrict__ Cf) {
    __shared__ __align__(16) float At[32 * 64];   // [k][m]
    __shared__ __align__(16) float Ws[32 * 64];   // [k][n]
    const int tid = threadIdx.x;
    const int tx = tid & 15, ty = tid >> 4;
    const int m0 = blockIdx.y * 64, n0 = blockIdx.x * 64;

    const int ar = tid >> 2;            // 0..63 : m within tile
    const int ac = (tid & 3) * 8;       // k-chunk base (0,8,16,24)
    const int wr = tid >> 3;            // 0..31 : k within tile
    const int wc = (tid & 7) * 8;       // n-chunk base (0..56)

    float acc[4][4] = {};

    for (int k0 = 0; k0 < D_DIM; k0 += 32) {
        float a8[8];
        if (Ab) {
            const short8 v = *(const short8*)(Ab + (size_t)(m0 + ar) * D_DIM + k0 + ac);
#pragma unroll
            for (int j = 0; j < 8; ++j) a8[j] = bf2f((ushort_t)v[j]);
        } else {
            const float4 f0 = *(const float4*)(Af + (size_t)(m0 + ar) * D_DIM + k0 + ac);
            const float4 f1 = *(const float4*)(Af + (size_t)(m0 + ar) * D_DIM + k0 + ac + 4);
            a8[0] = f0.x; a8[1] = f0.y; a8[2] = f0.z; a8[3] = f0.w;
            a8[4] = f1.x; a8[5] = f1.y; a8[6] = f1.z; a8[7] = f1.w;
        }
        const float4 g0 = *(const float4*)(W + (size_t)(k0 + wr) * D_DIM + n0 + wc);
        const float4 g1 = *(const float4*)(W + (size_t)(k0 + wr) * D_DIM + n0 + wc + 4);

        __syncthreads();   // previous iteration's LDS reads must be done
#pragma unroll
        for (int j = 0; j < 8; ++j) At[(ac + j) * 64 + ar] = a8[j];   // [k][m]
        *(float4*)(Ws + wr * 64 + wc)     = g0;                        // [k][n]
        *(float4*)(Ws + wr * 64 + wc + 4) = g1;
        __syncthreads();

#pragma unroll
        for (int k = 0; k < 32; ++k) {
            const float4 a4 = *(const float4*)(At + k * 64 + ty * 4);
            const float4 b4 = *(const float4*)(Ws + k * 64 + tx * 4);
            const float af[4] = { a4.x, a4.y, a4.z, a4.w };
            const float bf[4] = { b4.x, b4.y, b4.z, b4.w };
#pragma unroll
            for (int i = 0; i < 4; ++i)
#pragma unroll
                for (int j = 0; j < 4; ++j)
                    acc[i][j] += af[i] * bf[j];
        }
    }

#pragma unroll
    for (int i = 0; i < 4; ++i) {
        const int gm = m0 + ty * 4 + i;
#pragma unroll
        for (int j = 0; j < 4; ++j) {
            const int gn = n0 + tx * 4 + j;
            const float v = acc[i][j] + (bias ? bias[gn] : 0.0f);
            if (Cf) Cf[(size_t)gm * D_DIM + gn] = v;        // f32 output
            else    Cb[(size_t)gm * D_DIM + gn] = f2bf(v);  // bf16 output
        }
    }
}

// ---------------------------------------------------------------- attention
// UNCHANGED from round 5. Q,K,V,O merged row-major [B*S, D] bf16;
// head h = channels h*64..h*64+63. One thread per q-row, 64-key LDS tiles,
// exact online softmax in 16-key chunks.
__global__ __launch_bounds__(256, 1) void attn2_kernel(
        const ushort_t* __restrict__ Q, const ushort_t* __restrict__ K,
        const ushort_t* __restrict__ V, ushort_t* __restrict__ O) {
    __shared__ float Ks[64 * LKP];
    __shared__ float Vs[64 * LKP];
    const int bh  = blockIdx.x;               // 0..31
    const int b   = bh >> 4, h = bh & 15;
    const int qt  = 7 - (int)blockIdx.y;      // 0..7, biggest work first
    const int tid = threadIdx.x;
    const int s   = qt * 256 + tid;           // my query row within sequence
    const size_t rowbase = (size_t)b * S_LEN;
    const int ch0 = h * HD;

    float q[64];
    {
        const ushort_t* qp = Q + (rowbase + s) * D_DIM + ch0;
#pragma unroll
        for (int c = 0; c < 8; ++c) {
            const short8 v = *(const short8*)(qp + c * 8);
#pragma unroll
            for (int e = 0; e < 8; ++e) q[c * 8 + e] = bf2f((ushort_t)v[e]);
        }
    }

    float acc[64];
#pragma unroll
    for (int d = 0; d < 64; ++d) acc[d] = 0.0f;
    float m = -1e30f, l = 0.0f;

    const int ntiles = qt * 4 + 4;
    const int srow = tid >> 2;                // 0..63
    const int scol = (tid & 3) * 16;          // 0,16,32,48

    for (int tile = 0; tile < ntiles; ++tile) {
        const int kb = tile * 64;
        const ushort_t* kp = K + (rowbase + kb + srow) * D_DIM + ch0 + scol;
        const ushort_t* vp = V + (rowbase + kb + srow) * D_DIM + ch0 + scol;
        const short8 kA = *(const short8*)(kp);
        const short8 kB = *(const short8*)(kp + 8);
        const short8 vA = *(const short8*)(vp);
        const short8 vB = *(const short8*)(vp + 8);
        __syncthreads();
#pragma unroll
        for (int e = 0; e < 8; ++e) {
            Ks[srow * LKP + scol + e]     = bf2f((ushort_t)kA[e]);
            Ks[srow * LKP + scol + 8 + e] = bf2f((ushort_t)kB[e]);
            Vs[srow * LKP + scol + e]     = bf2f((ushort_t)vA[e]);
            Vs[srow * LKP + scol + 8 + e] = bf2f((ushort_t)vB[e]);
        }
        __syncthreads();

#pragma unroll
        for (int c4 = 0; c4 < 4; ++c4) {
            float sc[16];
            float cmax = -1e30f;
#pragma unroll
            for (int j = 0; j < 16; ++j) {
                const int kk = c4 * 16 + j;
                const float* kr = Ks + kk * LKP;
                float d0 = 0.f, d1 = 0.f, d2 = 0.f, d3 = 0.f;
#pragma unroll
                for (int dd = 0; dd < 16; ++dd) {
                    const float4 kv = *(const float4*)(kr + dd * 4);
                    d0 += q[dd * 4 + 0] * kv.x;
                    d1 += q[dd * 4 + 1] * kv.y;
                    d2 += q[dd * 4 + 2] * kv.z;
                    d3 += q[dd * 4 + 3] * kv.w;
                }
                float sv = (d0 + d1 + d2 + d3) * 0.125f;   // * hd^-0.5
                sv = (kb + kk <= s) ? sv : -1e30f;          // causal: key <= query
                sc[j] = sv;
                cmax = fmaxf(cmax, sv);
            }
            if (cmax > -1e29f) {
                const float mnew  = fmaxf(m, cmax);
                const float alpha = __expf(m - mnew);
                l *= alpha;
#pragma unroll
                for (int d = 0; d < 64; ++d) acc[d] *= alpha;
#pragma unroll
                for (int j = 0; j < 16; ++j) {
                    const float p = __expf(sc[j] - mnew);
                    l += p;
                    const float* vr = Vs + (c4 * 16 + j) * LKP;
#pragma unroll
                    for (int dd = 0; dd < 16; ++dd) {
                        const float4 vv = *(const float4*)(vr + dd * 4);
                        acc[dd * 4 + 0] += p * vv.x;
                        acc[dd * 4 + 1] += p * vv.y;
                        acc[dd * 4 + 2] += p * vv.z;
                        acc[dd * 4 + 3] += p * vv.w;
                    }
                }
                m = mnew;
            }
        }
    }

    const float inv = 1.0f / l;
    ushort_t* op = O + (rowbase + s) * D_DIM + ch0;
#pragma unroll
    for (int c = 0; c < 8; ++c) {
        short8 ov;
#pragma unroll
        for (int e = 0; e < 8; ++e) ov[e] = (short)f2bf(acc[c * 8 + e] * inv);
        *(short8*)(op + c * 8) = ov;
    }
}

// ---------------------------------------------------------------- launch
extern "C" void kernel_launch(void* const* d_in, const int* in_sizes, int n_in,
                              void* d_out, int out_size, void* d_ws, size_t ws_size,
                              hipStream_t stream) {
    const float* x  = (const float*)d_in[0];   // f32 inputs per reference
    const float* Wq = (const float*)d_in[1];
    const float* Wk = (const float*)d_in[2];
    const float* Wv = (const float*)d_in[3];
    const float* Wo = (const float*)d_in[4];
    const float* bo = (const float*)d_in[5];
    float* out = (float*)d_out;                // f32 output (reference returns f32)

    char* ws = (char*)d_ws;
    const size_t MB = 1024 * 1024;
    ushort_t* Qb = (ushort_t*)(ws + 0 * MB);   // [B*S, D] bf16, 8 MB each
    ushort_t* Kb = (ushort_t*)(ws + 8 * MB);
    ushort_t* Vb = (ushort_t*)(ws + 16 * MB);
    ushort_t* Ob = (ushort_t*)(ws + 24 * MB);  // total 32 MB

    const dim3 ggrid(16, 64);   // N/64, M/64
    gemm_naive_kernel<<<ggrid, 256, 0, stream>>>(x, nullptr, Wq, nullptr, Qb, nullptr);
    gemm_naive_kernel<<<ggrid, 256, 0, stream>>>(x, nullptr, Wk, nullptr, Kb, nullptr);
    gemm_naive_kernel<<<ggrid, 256, 0, stream>>>(x, nullptr, Wv, nullptr, Vb, nullptr);

    attn2_kernel<<<dim3(32, 8), 256, 0, stream>>>(Qb, Kb, Vb, Ob);

    gemm_naive_kernel<<<ggrid, 256, 0, stream>>>(nullptr, Ob, Wo, bo, nullptr, out);
}

// Round 8
// 259.532 us; speedup vs baseline: 5.5917x; 5.5917x over previous
//
#include <hip/hip_runtime.h>

typedef unsigned short ushort_t;
typedef unsigned int uint_t;
typedef __attribute__((ext_vector_type(8))) short short8;
typedef __attribute__((ext_vector_type(4))) float floatx4;

#define S_LEN 2048
#define D_DIM 1024
#define H_NUM 16
#define HD 64

__device__ __forceinline__ float bf2f(ushort_t u) {
    union { uint_t i; float f; } c; c.i = ((uint_t)u) << 16; return c.f;
}
__device__ __forceinline__ ushort_t f2bf(float f) {
    union { float f; uint_t i; } c; c.f = f;
    uint_t r = c.i + 0x7fffu + ((c.i >> 16) & 1u);
    return (ushort_t)(r >> 16);
}

// ---------------------------------------------------------------- cast x
__global__ __launch_bounds__(256, 4) void cast_x_kernel(
        const float* __restrict__ in, ushort_t* __restrict__ out) {
    const int idx = (blockIdx.x * 256 + threadIdx.x) * 4;
    const float4 v = *(const float4*)(in + idx);
    ushort4 o;
    o.x = f2bf(v.x); o.y = f2bf(v.y); o.z = f2bf(v.z); o.w = f2bf(v.w);
    *(ushort4*)(out + idx) = o;
}

// ---------------------------------------------------------------- transpose+cast (validated R3)
__global__ __launch_bounds__(256, 2) void transpose4_kernel(
        const float* __restrict__ W0, const float* __restrict__ W1,
        const float* __restrict__ W2, const float* __restrict__ W3,
        ushort_t* __restrict__ T0, ushort_t* __restrict__ T1,
        ushort_t* __restrict__ T2, ushort_t* __restrict__ T3) {
    const int z = blockIdx.z;
    const float* in  = (z == 0) ? W0 : (z == 1) ? W1 : (z == 2) ? W2 : W3;
    ushort_t*    out = (z == 0) ? T0 : (z == 1) ? T1 : (z == 2) ? T2 : T3;
    __shared__ __align__(16) ushort_t t[64][65];
    const int r0 = blockIdx.y * 64, c0 = blockIdx.x * 64;
    const int tr = threadIdx.x >> 4;
    const int tc = (threadIdx.x & 15) * 4;
#pragma unroll
    for (int i = 0; i < 4; ++i) {
        const int row = tr + i * 16;
        const float4 v = *(const float4*)(in + (size_t)(r0 + row) * D_DIM + c0 + tc);
        t[row][tc + 0] = f2bf(v.x); t[row][tc + 1] = f2bf(v.y);
        t[row][tc + 2] = f2bf(v.z); t[row][tc + 3] = f2bf(v.w);
    }
    __syncthreads();
#pragma unroll
    for (int i = 0; i < 4; ++i) {
        const int n = tr + i * 16;
        ushort4 v;
        v.x = t[tc + 0][n]; v.y = t[tc + 1][n];
        v.z = t[tc + 2][n]; v.w = t[tc + 3][n];
        *(ushort4*)(out + (size_t)(c0 + n) * D_DIM + r0 + tc) = v;
    }
}

// ---------------------------------------------------------------- MFMA GEMM tile (validated R3)
// C[M,N] = A[M,K] @ B with BT = B^T [N,K] row-major. 128x128 tile, BK=32,
// 4 waves 2x2 of 64x64, 16x16x32 bf16 MFMA, register->LDS staging.
__device__ __forceinline__ void gemm_tile(
        const ushort_t* __restrict__ A, const ushort_t* __restrict__ BT,
        const int m0, const int n0,
        ushort_t* As, ushort_t* Bs, floatx4 acc[4][4]) {
    const int tid  = threadIdx.x;
    const int w    = tid >> 6;
    const int wm   = (w >> 1) * 64;
    const int wn   = (w & 1) * 64;
    const int lrow = tid & 15;
    const int kq   = ((tid & 63) >> 4) * 8;

    const int flat0 = tid * 8;
    const int flat1 = (256 + tid) * 8;
    const int row0 = flat0 >> 5, kk0 = flat0 & 31;
    const int row1 = flat1 >> 5, kk1 = flat1 & 31;

    for (int k0 = 0; k0 < D_DIM; k0 += 32) {
        const short8 a0 = *(const short8*)(A  + (size_t)(m0 + row0) * D_DIM + k0 + kk0);
        const short8 b0 = *(const short8*)(BT + (size_t)(n0 + row0) * D_DIM + k0 + kk0);
        const short8 a1 = *(const short8*)(A  + (size_t)(m0 + row1) * D_DIM + k0 + kk1);
        const short8 b1 = *(const short8*)(BT + (size_t)(n0 + row1) * D_DIM + k0 + kk1);
        __syncthreads();
        *(short8*)(As + flat0) = a0; *(short8*)(Bs + flat0) = b0;
        *(short8*)(As + flat1) = a1; *(short8*)(Bs + flat1) = b1;
        __syncthreads();

        short8 av[4], bv[4];
#pragma unroll
        for (int i = 0; i < 4; ++i)
            av[i] = *(const short8*)(As + (wm + i * 16 + lrow) * 32 + kq);
#pragma unroll
        for (int j = 0; j < 4; ++j)
            bv[j] = *(const short8*)(Bs + (wn + j * 16 + lrow) * 32 + kq);
#pragma unroll
        for (int i = 0; i < 4; ++i)
#pragma unroll
            for (int j = 0; j < 4; ++j)
                acc[i][j] = __builtin_amdgcn_mfma_f32_16x16x32_bf16(
                    av[i], bv[j], acc[i][j], 0, 0, 0);
    }
}

// QKV: z picks weight/dest; writes merged row-major [B*S, D] bf16.
__global__ __launch_bounds__(256, 2) void gemm_qkv_kernel(
        const ushort_t* __restrict__ A,
        const ushort_t* __restrict__ WqT, const ushort_t* __restrict__ WkT,
        const ushort_t* __restrict__ WvT,
        ushort_t* __restrict__ Qo, ushort_t* __restrict__ Ko,
        ushort_t* __restrict__ Vo) {
    const ushort_t* BT = (blockIdx.z == 0) ? WqT : (blockIdx.z == 1) ? WkT : WvT;
    ushort_t* C        = (blockIdx.z == 0) ? Qo  : (blockIdx.z == 1) ? Ko  : Vo;
    __shared__ __align__(16) ushort_t As[128 * 32];
    __shared__ __align__(16) ushort_t Bs[128 * 32];
    const int m0 = blockIdx.y * 128, n0 = blockIdx.x * 128;

    floatx4 acc[4][4] = {};
    gemm_tile(A, BT, m0, n0, As, Bs, acc);

    const int tid = threadIdx.x;
    const int w = tid >> 6, wm = (w >> 1) * 64, wn = (w & 1) * 64;
    const int lrow = tid & 15;
    const int rquad = ((tid & 63) >> 4) * 4;
#pragma unroll
    for (int i = 0; i < 4; ++i) {
        const int mbase = m0 + wm + i * 16 + rquad;
#pragma unroll
        for (int j = 0; j < 4; ++j) {
            const int gn = n0 + wn + j * 16 + lrow;
#pragma unroll
            for (int r = 0; r < 4; ++r)
                C[(size_t)(mbase + r) * D_DIM + gn] = f2bf(acc[i][j][r]);
        }
    }
}

// Output projection: f32 out = A @ Wo + bo.
__global__ __launch_bounds__(256, 2) void gemm_out_kernel(
        const ushort_t* __restrict__ A, const ushort_t* __restrict__ WoT,
        const float* __restrict__ bias, float* __restrict__ C) {
    __shared__ __align__(16) ushort_t As[128 * 32];
    __shared__ __align__(16) ushort_t Bs[128 * 32];
    const int m0 = blockIdx.y * 128, n0 = blockIdx.x * 128;

    floatx4 acc[4][4] = {};
    gemm_tile(A, WoT, m0, n0, As, Bs, acc);

    const int tid = threadIdx.x;
    const int w = tid >> 6, wm = (w >> 1) * 64, wn = (w & 1) * 64;
    const int lrow = tid & 15;
    const int rquad = ((tid & 63) >> 4) * 4;
#pragma unroll
    for (int i = 0; i < 4; ++i) {
        const int mbase = m0 + wm + i * 16 + rquad;
#pragma unroll
        for (int j = 0; j < 4; ++j) {
            const int gn = n0 + wn + j * 16 + lrow;
            const float badd = bias[gn];
#pragma unroll
            for (int r = 0; r < 4; ++r)
                C[(size_t)(mbase + r) * D_DIM + gn] = acc[i][j][r] + badd;
        }
    }
}

// ---------------------------------------------------------------- MFMA flash attention
// Q,K,V,O merged row-major [B*S, D] bf16; head h = channels h*64..h*64+63.
// Grid (32 bh, 16 qtiles). Block: 256 thr = 4 waves; block q-tile = 128 rows,
// wave = 32 rows. 64-key tiles staged in LDS (K natural, V transposed).
// S = Q K^T via 16x16x32 MFMA; online softmax on C-layout; P -> LDS (bf16)
// -> A-frags; O += P V via MFMA. All LDS rows stride 33 dwords (66 bf16).
__global__ __launch_bounds__(256, 1) void attn_mfma_kernel(
        const ushort_t* __restrict__ Q, const ushort_t* __restrict__ K,
        const ushort_t* __restrict__ V, ushort_t* __restrict__ O) {
    __shared__ uint_t Ks32[64 * 33];       // [key][d-pairs]
    __shared__ uint_t Vt32[64 * 33];       // [d][key-pairs] (transposed V)
    __shared__ uint_t Ps32[4][32 * 33];    // per-wave P [row][key-pairs]

    const int bh  = blockIdx.x;
    const int b   = bh >> 4, h = bh & 15;
    const int qt  = 15 - (int)blockIdx.y;   // biggest work first
    const int q0  = qt * 128;
    const int tid = threadIdx.x;
    const int wq  = tid >> 6;
    const int lane = tid & 63;
    const int col  = lane & 15;
    const int quad = lane >> 4;
    const int qw0  = q0 + wq * 32;          // wave's first q-row
    const size_t rowbase = (size_t)b * S_LEN;
    const int ch0 = h * HD;

    // Q A-fragments: A[m = qrow][k = d]; lane holds A[m=col][k=quad*8+e]
    short8 aq[2][2];
#pragma unroll
    for (int i = 0; i < 2; ++i)
#pragma unroll
        for (int kc = 0; kc < 2; ++kc)
            aq[i][kc] = *(const short8*)(Q + (rowbase + qw0 + i * 16 + col) * D_DIM
                                           + ch0 + kc * 32 + quad * 8);

    floatx4 oacc[2][4] = {};
    float mrun[2][4], lrun[2][4];
#pragma unroll
    for (int i = 0; i < 2; ++i)
#pragma unroll
        for (int r = 0; r < 4; ++r) { mrun[i][r] = -1e30f; lrun[i][r] = 0.0f; }

    const int ntiles = qt * 2 + 2;
    const int skey = tid >> 2;           // staging: key row 0..63
    const int schk = tid & 3;            // d-chunk 0..3
    const int sd0  = schk * 16;

    for (int t = 0; t < ntiles; ++t) {
        const int kb = t * 64;
        __syncthreads();   // previous tile's LDS reads complete
        // ---- stage K tile (dword copies, natural [key][d])
        {
            const uint_t* kg = (const uint_t*)(K + (rowbase + kb + skey) * D_DIM + ch0 + sd0);
            const uint4 u0 = *(const uint4*)(kg);
            const uint4 u1 = *(const uint4*)(kg + 4);
            uint_t* kd = Ks32 + skey * 33 + schk * 8;
            kd[0] = u0.x; kd[1] = u0.y; kd[2] = u0.z; kd[3] = u0.w;
            kd[4] = u1.x; kd[5] = u1.y; kd[6] = u1.z; kd[7] = u1.w;
        }
        // ---- stage V tile transposed: Vt[d][key]
        {
            const ushort_t* vg = V + (rowbase + kb + skey) * D_DIM + ch0 + sd0;
            const short8 v0 = *(const short8*)(vg);
            const short8 v1 = *(const short8*)(vg + 8);
            ushort_t* vt = (ushort_t*)Vt32;
#pragma unroll
            for (int e = 0; e < 8; ++e) vt[(sd0 + e) * 66 + skey]     = (ushort_t)v0[e];
#pragma unroll
            for (int e = 0; e < 8; ++e) vt[(sd0 + 8 + e) * 66 + skey] = (ushort_t)v1[e];
        }
        __syncthreads();

        if (kb <= qw0 + 31) {            // wave-uniform: tile has valid keys for this wave
            // ---- S = Q K^T
            floatx4 sa[2][4] = {};
#pragma unroll
            for (int kc = 0; kc < 2; ++kc)
#pragma unroll
                for (int j = 0; j < 4; ++j) {
                    union { short8 s; uint_t u[4]; } bk;
                    const uint_t* kp = Ks32 + (j * 16 + col) * 33 + kc * 16 + quad * 4;
                    bk.u[0] = kp[0]; bk.u[1] = kp[1]; bk.u[2] = kp[2]; bk.u[3] = kp[3];
#pragma unroll
                    for (int i = 0; i < 2; ++i)
                        sa[i][j] = __builtin_amdgcn_mfma_f32_16x16x32_bf16(
                            aq[i][kc], bk.s, sa[i][j], 0, 0, 0);
                }

            const bool needmask = (kb + 63 > qw0);
            // ---- scale + causal mask
#pragma unroll
            for (int i = 0; i < 2; ++i)
#pragma unroll
                for (int j = 0; j < 4; ++j)
#pragma unroll
                    for (int r = 0; r < 4; ++r) {
                        float v = sa[i][j][r] * 0.125f;
                        if (needmask) {
                            const int row = qw0 + i * 16 + quad * 4 + r;
                            const int key = kb + j * 16 + col;
                            v = (key <= row) ? v : -1e30f;
                        }
                        sa[i][j][r] = v;
                    }
            // ---- online softmax per row (row = i*16 + quad*4 + r; cols across lanes)
#pragma unroll
            for (int i = 0; i < 2; ++i)
#pragma unroll
                for (int r = 0; r < 4; ++r) {
                    float mx = fmaxf(fmaxf(sa[i][0][r], sa[i][1][r]),
                                     fmaxf(sa[i][2][r], sa[i][3][r]));
                    mx = fmaxf(mx, __shfl_xor(mx, 1));
                    mx = fmaxf(mx, __shfl_xor(mx, 2));
                    mx = fmaxf(mx, __shfl_xor(mx, 4));
                    mx = fmaxf(mx, __shfl_xor(mx, 8));
                    const float mn = fmaxf(mrun[i][r], mx);
                    const float al = __expf(mrun[i][r] - mn);
                    mrun[i][r] = mn;
                    float rs = 0.0f;
#pragma unroll
                    for (int j = 0; j < 4; ++j) {
                        const float p = __expf(sa[i][j][r] - mn);
                        sa[i][j][r] = p;
                        rs += p;
                    }
                    rs += __shfl_xor(rs, 1);
                    rs += __shfl_xor(rs, 2);
                    rs += __shfl_xor(rs, 4);
                    rs += __shfl_xor(rs, 8);
                    lrun[i][r] = lrun[i][r] * al + rs;
#pragma unroll
                    for (int jd = 0; jd < 4; ++jd) oacc[i][jd][r] *= al;
                }
            // ---- write P (bf16) to this wave's LDS region
            {
                ushort_t* pw = (ushort_t*)Ps32[wq];
#pragma unroll
                for (int i = 0; i < 2; ++i)
#pragma unroll
                    for (int j = 0; j < 4; ++j)
#pragma unroll
                        for (int r = 0; r < 4; ++r)
                            pw[(i * 16 + quad * 4 + r) * 66 + j * 16 + col] =
                                f2bf(sa[i][j][r]);
            }
            asm volatile("s_waitcnt lgkmcnt(0)" ::: "memory");   // wave-local RAW
            // ---- O += P V
#pragma unroll
            for (int kc = 0; kc < 2; ++kc) {
                union { short8 s; uint_t u[4]; } ap[2];
#pragma unroll
                for (int i = 0; i < 2; ++i) {
                    const uint_t* pp = Ps32[wq] + (i * 16 + col) * 33 + kc * 16 + quad * 4;
                    ap[i].u[0] = pp[0]; ap[i].u[1] = pp[1];
                    ap[i].u[2] = pp[2]; ap[i].u[3] = pp[3];
                }
#pragma unroll
                for (int jd = 0; jd < 4; ++jd) {
                    union { short8 s; uint_t u[4]; } bv;
                    const uint_t* vp = Vt32 + (jd * 16 + col) * 33 + kc * 16 + quad * 4;
                    bv.u[0] = vp[0]; bv.u[1] = vp[1]; bv.u[2] = vp[2]; bv.u[3] = vp[3];
#pragma unroll
                    for (int i = 0; i < 2; ++i)
                        oacc[i][jd] = __builtin_amdgcn_mfma_f32_16x16x32_bf16(
                            ap[i].s, bv.s, oacc[i][jd], 0, 0, 0);
                }
            }
        }
    }

    // ---- epilogue: O row-major bf16, normalized
#pragma unroll
    for (int i = 0; i < 2; ++i)
#pragma unroll
        for (int r = 0; r < 4; ++r) {
            const int row = qw0 + i * 16 + quad * 4 + r;
            const float inv = 1.0f / lrun[i][r];
#pragma unroll
            for (int jd = 0; jd < 4; ++jd)
                O[(rowbase + row) * D_DIM + ch0 + jd * 16 + col] =
                    f2bf(oacc[i][jd][r] * inv);
        }
}

// ---------------------------------------------------------------- launch
extern "C" void kernel_launch(void* const* d_in, const int* in_sizes, int n_in,
                              void* d_out, int out_size, void* d_ws, size_t ws_size,
                              hipStream_t stream) {
    const float* x  = (const float*)d_in[0];
    const float* Wq = (const float*)d_in[1];
    const float* Wk = (const float*)d_in[2];
    const float* Wv = (const float*)d_in[3];
    const float* Wo = (const float*)d_in[4];
    const float* bo = (const float*)d_in[5];
    float* out = (float*)d_out;                // f32 output

    char* ws = (char*)d_ws;
    const size_t MB = 1024 * 1024;
    ushort_t* xb  = (ushort_t*)(ws + 0 * MB);   // 8 MB
    ushort_t* WqT = (ushort_t*)(ws + 8 * MB);   // 2 MB each
    ushort_t* WkT = (ushort_t*)(ws + 10 * MB);
    ushort_t* WvT = (ushort_t*)(ws + 12 * MB);
    ushort_t* WoT = (ushort_t*)(ws + 14 * MB);
    ushort_t* Qb  = (ushort_t*)(ws + 16 * MB);  // [B*S, D] bf16, 8 MB each
    ushort_t* Kb  = (ushort_t*)(ws + 24 * MB);
    ushort_t* Vb  = (ushort_t*)(ws + 32 * MB);
    ushort_t* Ob  = (ushort_t*)(ws + 40 * MB);  // total 48 MB

    cast_x_kernel<<<4096, 256, 0, stream>>>(x, xb);
    transpose4_kernel<<<dim3(16, 16, 4), 256, 0, stream>>>(
        Wq, Wk, Wv, Wo, WqT, WkT, WvT, WoT);

    gemm_qkv_kernel<<<dim3(8, 32, 3), 256, 0, stream>>>(
        xb, WqT, WkT, WvT, Qb, Kb, Vb);

    attn_mfma_kernel<<<dim3(32, 16), 256, 0, stream>>>(Qb, Kb, Vb, Ob);

    gemm_out_kernel<<<dim3(8, 32), 256, 0, stream>>>(Ob, WoT, bo, out);
}